// Round 1
// baseline (1024.090 us; speedup 1.0000x reference)
//
#include <hip/hip_runtime.h>
#include <hip/hip_bf16.h>
#include <math.h>

#define BB 8
#define HS 64
#define WS 64
#define LL 4096
#define DM 96
#define DI 192
#define NS 16
#define RR 6
#define KK 4
#define NCH 32
#define LC 128
#define EPSN 1e-6f

__device__ __forceinline__ float fsilu(float x) { return x / (1.f + __expf(-x)); }
__device__ __forceinline__ float fsoftplus(float x) {
    return (x > 20.f) ? x : log1pf(__expf(x));
}
// spatial index l for direction k at scan step t (also equals inverse map)
__device__ __forceinline__ int lmap(int k, int t) {
    int tt = (k >= 2) ? (LL - 1 - t) : t;
    if (k & 1) tt = ((tt & 63) << 6) | (tt >> 6);
    return tt;
}

// ---------------- K1: in_proj + silu(z) ----------------
__global__ __launch_bounds__(384) void k_inproj(const float* __restrict__ x,
        const float* __restrict__ Win, float* __restrict__ xx, float* __restrict__ zs) {
    __shared__ float xrow[8][96];
    int p0 = blockIdx.x * 8;
    int tid = threadIdx.x;
    for (int e = tid; e < 8 * 96; e += 384) xrow[e / 96][e % 96] = x[(size_t)p0 * 96 + e];
    __syncthreads();
    const float* wr = Win + tid * 96;
    float acc[8] = {0.f, 0.f, 0.f, 0.f, 0.f, 0.f, 0.f, 0.f};
    #pragma unroll 4
    for (int kk = 0; kk < 96; ++kk) {
        float wv = wr[kk];
        #pragma unroll
        for (int p = 0; p < 8; ++p) acc[p] += wv * xrow[p][kk];
    }
    if (tid < DI) {
        #pragma unroll
        for (int p = 0; p < 8; ++p) xx[(size_t)(p0 + p) * DI + tid] = acc[p];
    } else {
        int d = tid - DI;
        #pragma unroll
        for (int p = 0; p < 8; ++p) zs[(size_t)(p0 + p) * DI + d] = fsilu(acc[p]);
    }
}

// ---------------- K2: depthwise conv 3x3 + silu + init y0 = xc * sum_k Ds ----------------
__global__ __launch_bounds__(256) void k_conv(const float* __restrict__ xx,
        const float* __restrict__ cw, const float* __restrict__ cb,
        const float* __restrict__ Ds, float* __restrict__ xc, float* __restrict__ y0) {
    int idx = blockIdx.x * 256 + threadIdx.x;   // = P*192 + d
    int d = idx % DI; int P = idx / DI;
    int l = P & (LL - 1); int h = l >> 6; int w = l & 63;
    float acc = cb[d];
    #pragma unroll
    for (int i = 0; i < 3; ++i) {
        int hh = h + i - 1;
        if ((unsigned)hh < 64u) {
            #pragma unroll
            for (int j = 0; j < 3; ++j) {
                int ww = w + j - 1;
                if ((unsigned)ww < 64u)
                    acc += xx[(size_t)(P + (i - 1) * 64 + (j - 1)) * DI + d] * cw[d * 9 + i * 3 + j];
            }
        }
    }
    float s = fsilu(acc);
    float sd = Ds[d] + Ds[DI + d] + Ds[2 * DI + d] + Ds[3 * DI + d];
    xc[idx] = s;
    y0[idx] = s * sd;
}

// ---------------- K3: x_dbl = xs @ xpw^T  -> dts_raw / Bs / Cs (scan order) ----------------
__global__ __launch_bounds__(256) void k_xdbl(const float* __restrict__ xc,
        const float* __restrict__ xpw, float* __restrict__ dts_raw,
        float* __restrict__ Bs, float* __restrict__ Cs) {
    __shared__ float xt[64][193];
    int tid = threadIdx.x;
    int p0 = blockIdx.x * 64;
    for (int e = tid; e < 64 * DI; e += 256) xt[e / DI][e % DI] = xc[(size_t)p0 * DI + e];
    __syncthreads();
    int p4 = tid >> 2, q = tid & 3;
    int P = p0 + p4;
    int b = P >> 12; int l = P & (LL - 1);
    int lt = ((l & 63) << 6) | (l >> 6);
    int tk[4] = { l, lt, LL - 1 - l, LL - 1 - lt };
    for (int c4 = 0; c4 < 38; ++c4) {
        float a0 = 0.f, a1 = 0.f, a2 = 0.f, a3 = 0.f;
        const float* w0 = xpw + (size_t)c4 * 4 * DI;
        #pragma unroll 8
        for (int i = 0; i < 48; ++i) {
            int j = i * 4 + q;
            float xv = xt[p4][j];
            a0 += xv * w0[j];
            a1 += xv * w0[DI + j];
            a2 += xv * w0[2 * DI + j];
            a3 += xv * w0[3 * DI + j];
        }
        float accs[4] = {a0, a1, a2, a3};
        #pragma unroll
        for (int cc = 0; cc < 4; ++cc) {
            float s = accs[cc];
            s += __shfl_xor(s, 1);
            s += __shfl_xor(s, 2);
            if (q == 0) {
                int c = c4 * 4 + cc;
                int k = c / 38, c2 = c % 38;
                size_t it = ((size_t)(b * KK + k) * LL + tk[k]);
                if (c2 < RR)            dts_raw[it * RR + c2] = s;
                else if (c2 < RR + NS)  Bs[it * NS + (c2 - RR)] = s;
                else                    Cs[it * NS + (c2 - RR - NS)] = s;
            }
        }
    }
}

// ---------------- K5a: chunked scan pass 1 (chunk summaries, h_in = 0) ----------------
__global__ __launch_bounds__(192) void k_scan1(const float* __restrict__ xc,
        const float* __restrict__ dts_raw, const float* __restrict__ Bsg,
        const float* __restrict__ A_logs, const float* __restrict__ dtw,
        const float* __restrict__ dtb,
        float* __restrict__ aprod, float* __restrict__ hpart) {
    __shared__ float dts_s[LC * RR];
    __shared__ float bs_s[LC * NS];
    int bi = blockIdx.x;
    int b = bi >> 7; int rem = bi & 127; int k = rem >> 5; int c0 = rem & 31;
    int t0 = c0 * LC;
    int d = threadIdx.x;
    size_t bkL = (size_t)(b * KK + k) * LL;
    for (int e = d; e < LC * RR; e += DI) dts_s[e] = dts_raw[(bkL + t0) * RR + e];
    for (int e = d; e < LC * NS; e += DI) bs_s[e] = Bsg[(bkL + t0) * NS + e];
    __syncthreads();
    int kd = k * DI + d;
    float Ar[NS];
    #pragma unroll
    for (int n = 0; n < NS; ++n) Ar[n] = -__expf(A_logs[(size_t)kd * NS + n]);
    float dw[RR];
    #pragma unroll
    for (int r = 0; r < RR; ++r) dw[r] = dtw[kd * RR + r];
    float bias = dtb[kd];
    float h[NS];
    #pragma unroll
    for (int n = 0; n < NS; ++n) h[n] = 0.f;
    float asum = 0.f;
    const float* xcb = xc + (size_t)b * LL * DI + d;
    for (int t = 0; t < LC; ++t) {
        float dtr = bias;
        #pragma unroll
        for (int r = 0; r < RR; ++r) dtr += dts_s[t * RR + r] * dw[r];
        float dt = fsoftplus(dtr);
        int lx = lmap(k, t0 + t);
        float u = xcb[(size_t)lx * DI];
        float dtu = dt * u;
        asum += dt;
        #pragma unroll
        for (int n = 0; n < NS; ++n)
            h[n] = h[n] * __expf(dt * Ar[n]) + dtu * bs_s[t * NS + n];
    }
    size_t base = ((size_t)bi * DI + d) * NS;
    #pragma unroll
    for (int n = 0; n < NS; ++n) {
        hpart[base + n] = h[n];
        aprod[base + n] = __expf(asum * Ar[n]);
    }
}

// ---------------- K5b: propagate chunk-boundary states ----------------
__global__ __launch_bounds__(256) void k_mid(const float* __restrict__ aprod,
        const float* __restrict__ hpart, float* __restrict__ hin) {
    int g = blockIdx.x * 256 + threadIdx.x;   // B*K*DI*NS threads
    int bk = g / (DI * NS);
    int rem = g % (DI * NS);
    float h = 0.f;
    for (int c = 0; c < NCH; ++c) {
        size_t ix = ((size_t)(bk * NCH + c) * DI * NS) + rem;
        hin[ix] = h;
        h = aprod[ix] * h + hpart[ix];
    }
}

// ---------------- K5c: chunked scan pass 2 (full scan, emit y, atomic merge) ----------------
__global__ __launch_bounds__(192) void k_scan2(const float* __restrict__ xc,
        const float* __restrict__ dts_raw, const float* __restrict__ Bsg,
        const float* __restrict__ Csg, const float* __restrict__ A_logs,
        const float* __restrict__ dtw, const float* __restrict__ dtb,
        const float* __restrict__ hin, float* __restrict__ y0) {
    __shared__ float dts_s[LC * RR];
    __shared__ float bs_s[LC * NS];
    __shared__ float cs_s[LC * NS];
    int bi = blockIdx.x;
    int b = bi >> 7; int rem = bi & 127; int k = rem >> 5; int c0 = rem & 31;
    int t0 = c0 * LC;
    int d = threadIdx.x;
    size_t bkL = (size_t)(b * KK + k) * LL;
    for (int e = d; e < LC * RR; e += DI) dts_s[e] = dts_raw[(bkL + t0) * RR + e];
    for (int e = d; e < LC * NS; e += DI) bs_s[e] = Bsg[(bkL + t0) * NS + e];
    for (int e = d; e < LC * NS; e += DI) cs_s[e] = Csg[(bkL + t0) * NS + e];
    __syncthreads();
    int kd = k * DI + d;
    float Ar[NS];
    #pragma unroll
    for (int n = 0; n < NS; ++n) Ar[n] = -__expf(A_logs[(size_t)kd * NS + n]);
    float dw[RR];
    #pragma unroll
    for (int r = 0; r < RR; ++r) dw[r] = dtw[kd * RR + r];
    float bias = dtb[kd];
    size_t base = ((size_t)bi * DI + d) * NS;
    float h[NS];
    #pragma unroll
    for (int n = 0; n < NS; ++n) h[n] = hin[base + n];
    const float* xcb = xc + (size_t)b * LL * DI + d;
    float* y0b = y0 + (size_t)b * LL * DI + d;
    for (int t = 0; t < LC; ++t) {
        float dtr = bias;
        #pragma unroll
        for (int r = 0; r < RR; ++r) dtr += dts_s[t * RR + r] * dw[r];
        float dt = fsoftplus(dtr);
        int lx = lmap(k, t0 + t);
        float u = xcb[(size_t)lx * DI];
        float dtu = dt * u;
        float y = 0.f;
        #pragma unroll
        for (int n = 0; n < NS; ++n) {
            h[n] = h[n] * __expf(dt * Ar[n]) + dtu * bs_s[t * NS + n];
            y += h[n] * cs_s[t * NS + n];
        }
        atomicAdd(&y0b[(size_t)lx * DI], y);
    }
}

// ---------------- K6: LayerNorm + gate + out_proj ----------------
__global__ __launch_bounds__(256) void k_final(const float* __restrict__ y0,
        const float* __restrict__ zs, const float* __restrict__ nw,
        const float* __restrict__ nb, const float* __restrict__ Wout,
        float* __restrict__ out) {
    __shared__ float gs[4][DI];
    int tid = threadIdx.x;
    int wv = tid >> 6, lane = tid & 63;
    int P = blockIdx.x * 4 + wv;
    float v[3];
    #pragma unroll
    for (int j = 0; j < 3; ++j) v[j] = y0[(size_t)P * DI + lane + 64 * j];
    float s = v[0] + v[1] + v[2];
    #pragma unroll
    for (int o = 32; o; o >>= 1) s += __shfl_xor(s, o);
    float mean = s * (1.f / 192.f);
    float ss = 0.f;
    #pragma unroll
    for (int j = 0; j < 3; ++j) { float dd = v[j] - mean; ss += dd * dd; }
    #pragma unroll
    for (int o = 32; o; o >>= 1) ss += __shfl_xor(ss, o);
    float rstd = rsqrtf(ss * (1.f / 192.f) + EPSN);
    #pragma unroll
    for (int j = 0; j < 3; ++j) {
        int c = lane + 64 * j;
        gs[wv][c] = ((v[j] - mean) * rstd * nw[c] + nb[c]) * zs[(size_t)P * DI + c];
    }
    __syncthreads();
    for (int idx = tid; idx < 4 * DM; idx += 256) {
        int p = idx / DM, o = idx % DM;
        const float* wr = Wout + o * DI;
        const float* gr = gs[p];
        float acc = 0.f;
        #pragma unroll 8
        for (int dd2 = 0; dd2 < DI; ++dd2) acc += gr[dd2] * wr[dd2];
        out[(size_t)(blockIdx.x * 4 + p) * DM + o] = acc;
    }
}

extern "C" void kernel_launch(void* const* d_in, const int* in_sizes, int n_in,
                              void* d_out, int out_size, void* d_ws, size_t ws_size,
                              hipStream_t stream) {
    const float* x      = (const float*)d_in[0];
    const float* in_w   = (const float*)d_in[1];
    const float* conv_w = (const float*)d_in[2];
    const float* conv_b = (const float*)d_in[3];
    const float* xpw    = (const float*)d_in[4];
    const float* dtw    = (const float*)d_in[5];
    const float* A_logs = (const float*)d_in[6];
    const float* Ds     = (const float*)d_in[7];
    const float* dtb    = (const float*)d_in[8];
    const float* nw     = (const float*)d_in[9];
    const float* nb     = (const float*)d_in[10];
    const float* out_w  = (const float*)d_in[11];
    float* out = (float*)d_out;

    char* ws = (char*)d_ws;
    size_t off = 0;
    auto alloc = [&](size_t n) { float* p = (float*)(ws + off); off += n * sizeof(float); return p; };
    float* xx  = alloc((size_t)BB * LL * DI);
    float* zs  = alloc((size_t)BB * LL * DI);
    float* xc  = alloc((size_t)BB * LL * DI);
    float* y0  = alloc((size_t)BB * LL * DI);
    float* dts = alloc((size_t)BB * KK * LL * RR);
    float* Bsb = alloc((size_t)BB * KK * LL * NS);
    float* Csb = alloc((size_t)BB * KK * LL * NS);
    float* apr = alloc((size_t)BB * KK * NCH * DI * NS);
    float* hpp = alloc((size_t)BB * KK * NCH * DI * NS);
    float* hin = alloc((size_t)BB * KK * NCH * DI * NS);

    k_inproj<<<BB * LL / 8, 384, 0, stream>>>(x, in_w, xx, zs);
    k_conv<<<BB * LL * DI / 256, 256, 0, stream>>>(xx, conv_w, conv_b, Ds, xc, y0);
    k_xdbl<<<BB * LL / 64, 256, 0, stream>>>(xc, xpw, dts, Bsb, Csb);
    k_scan1<<<BB * KK * NCH, DI, 0, stream>>>(xc, dts, Bsb, A_logs, dtw, dtb, apr, hpp);
    k_mid<<<(BB * KK * DI * NS) / 256, 256, 0, stream>>>(apr, hpp, hin);
    k_scan2<<<BB * KK * NCH, DI, 0, stream>>>(xc, dts, Bsb, Csb, A_logs, dtw, dtb, hin, y0);
    k_final<<<BB * LL / 4, 256, 0, stream>>>(y0, zs, nw, nb, out_w, out);
}

// Round 3
// 797.917 us; speedup vs baseline: 1.2835x; 1.2835x over previous
//
#include <hip/hip_runtime.h>
#include <hip/hip_bf16.h>
#include <math.h>

#define BB 8
#define HS 64
#define WS 64
#define LL 4096
#define DM 96
#define DI 192
#define NS 16
#define RR 6
#define KK 4
#define NCH 32
#define LC 128
#define EPSN 1e-6f

__device__ __forceinline__ float fsilu(float x) { return x / (1.f + __expf(-x)); }
__device__ __forceinline__ float fsoftplus(float x) {
    return (x > 20.f) ? x : log1pf(__expf(x));
}
// spatial index l for direction k at scan step t (also equals inverse map)
__device__ __forceinline__ int lmap(int k, int t) {
    int tt = (k >= 2) ? (LL - 1 - t) : t;
    if (k & 1) tt = ((tt & 63) << 6) | (tt >> 6);
    return tt;
}

// ---------------- K1: in_proj + silu(z) ----------------
__global__ __launch_bounds__(384) void k_inproj(const float* __restrict__ x,
        const float* __restrict__ Win, float* __restrict__ xx, float* __restrict__ zs) {
    __shared__ float xrow[8][96];
    int p0 = blockIdx.x * 8;
    int tid = threadIdx.x;
    for (int e = tid; e < 8 * 96; e += 384) xrow[e / 96][e % 96] = x[(size_t)p0 * 96 + e];
    __syncthreads();
    const float* wr = Win + tid * 96;
    float acc[8] = {0.f, 0.f, 0.f, 0.f, 0.f, 0.f, 0.f, 0.f};
    #pragma unroll 4
    for (int kk = 0; kk < 96; ++kk) {
        float wv = wr[kk];
        #pragma unroll
        for (int p = 0; p < 8; ++p) acc[p] += wv * xrow[p][kk];
    }
    if (tid < DI) {
        #pragma unroll
        for (int p = 0; p < 8; ++p) xx[(size_t)(p0 + p) * DI + tid] = acc[p];
    } else {
        int d = tid - DI;
        #pragma unroll
        for (int p = 0; p < 8; ++p) zs[(size_t)(p0 + p) * DI + d] = fsilu(acc[p]);
    }
}

// ---------------- K2: depthwise conv 3x3 + silu + init y0 = xc * sum_k Ds ----------------
__global__ __launch_bounds__(256) void k_conv(const float* __restrict__ xx,
        const float* __restrict__ cw, const float* __restrict__ cb,
        const float* __restrict__ Ds, float* __restrict__ xc, float* __restrict__ y0) {
    int idx = blockIdx.x * 256 + threadIdx.x;   // = P*192 + d
    int d = idx % DI; int P = idx / DI;
    int l = P & (LL - 1); int h = l >> 6; int w = l & 63;
    float acc = cb[d];
    #pragma unroll
    for (int i = 0; i < 3; ++i) {
        int hh = h + i - 1;
        if ((unsigned)hh < 64u) {
            #pragma unroll
            for (int j = 0; j < 3; ++j) {
                int ww = w + j - 1;
                if ((unsigned)ww < 64u)
                    acc += xx[(size_t)(P + (i - 1) * 64 + (j - 1)) * DI + d] * cw[d * 9 + i * 3 + j];
            }
        }
    }
    float s = fsilu(acc);
    float sd = Ds[d] + Ds[DI + d] + Ds[2 * DI + d] + Ds[3 * DI + d];
    xc[idx] = s;
    y0[idx] = s * sd;
}

// ---------------- K3: x_dbl = xs @ xpw^T  -> dts_raw / Bs / Cs (scan order) ----------------
__global__ __launch_bounds__(256) void k_xdbl(const float* __restrict__ xc,
        const float* __restrict__ xpw, float* __restrict__ dts_raw,
        float* __restrict__ Bs, float* __restrict__ Cs) {
    __shared__ float xt[64][193];
    int tid = threadIdx.x;
    int p0 = blockIdx.x * 64;
    for (int e = tid; e < 64 * DI; e += 256) xt[e / DI][e % DI] = xc[(size_t)p0 * DI + e];
    __syncthreads();
    int p4 = tid >> 2, q = tid & 3;
    int P = p0 + p4;
    int b = P >> 12; int l = P & (LL - 1);
    int lt = ((l & 63) << 6) | (l >> 6);
    int tk[4] = { l, lt, LL - 1 - l, LL - 1 - lt };
    for (int c4 = 0; c4 < 38; ++c4) {
        float a0 = 0.f, a1 = 0.f, a2 = 0.f, a3 = 0.f;
        const float* w0 = xpw + (size_t)c4 * 4 * DI;
        #pragma unroll 8
        for (int i = 0; i < 48; ++i) {
            int j = i * 4 + q;
            float xv = xt[p4][j];
            a0 += xv * w0[j];
            a1 += xv * w0[DI + j];
            a2 += xv * w0[2 * DI + j];
            a3 += xv * w0[3 * DI + j];
        }
        float accs[4] = {a0, a1, a2, a3};
        #pragma unroll
        for (int cc = 0; cc < 4; ++cc) {
            float s = accs[cc];
            s += __shfl_xor(s, 1);
            s += __shfl_xor(s, 2);
            if (q == 0) {
                int c = c4 * 4 + cc;
                int k = c / 38, c2 = c % 38;
                size_t it = ((size_t)(b * KK + k) * LL + tk[k]);
                if (c2 < RR)            dts_raw[it * RR + c2] = s;
                else if (c2 < RR + NS)  Bs[it * NS + (c2 - RR)] = s;
                else                    Cs[it * NS + (c2 - RR - NS)] = s;
            }
        }
    }
}

// ---------------- K5a: chunked scan pass 1 (chunk summaries, h_in = 0) ----------------
__global__ __launch_bounds__(192) void k_scan1(const float* __restrict__ xc,
        const float* __restrict__ dts_raw, const float* __restrict__ Bsg,
        const float* __restrict__ A_logs, const float* __restrict__ dtw,
        const float* __restrict__ dtb,
        float* __restrict__ aprod, float* __restrict__ hpart) {
    __shared__ float dts_s[LC * RR];
    __shared__ float bs_s[LC * NS];
    int bi = blockIdx.x;
    int b = bi >> 7; int rem = bi & 127; int k = rem >> 5; int c0 = rem & 31;
    int t0 = c0 * LC;
    int d = threadIdx.x;
    size_t bkL = (size_t)(b * KK + k) * LL;
    for (int e = d; e < LC * RR; e += DI) dts_s[e] = dts_raw[(bkL + t0) * RR + e];
    for (int e = d; e < LC * NS; e += DI) bs_s[e] = Bsg[(bkL + t0) * NS + e];
    __syncthreads();
    int kd = k * DI + d;
    float Ar[NS];
    #pragma unroll
    for (int n = 0; n < NS; ++n) Ar[n] = -__expf(A_logs[(size_t)kd * NS + n]);
    float dw[RR];
    #pragma unroll
    for (int r = 0; r < RR; ++r) dw[r] = dtw[kd * RR + r];
    float bias = dtb[kd];
    float h[NS];
    #pragma unroll
    for (int n = 0; n < NS; ++n) h[n] = 0.f;
    float asum = 0.f;
    const float* xcb = xc + (size_t)b * LL * DI + d;
    for (int t = 0; t < LC; ++t) {
        float dtr = bias;
        #pragma unroll
        for (int r = 0; r < RR; ++r) dtr += dts_s[t * RR + r] * dw[r];
        float dt = fsoftplus(dtr);
        int lx = lmap(k, t0 + t);
        float u = xcb[(size_t)lx * DI];
        float dtu = dt * u;
        asum += dt;
        #pragma unroll
        for (int n = 0; n < NS; ++n)
            h[n] = h[n] * __expf(dt * Ar[n]) + dtu * bs_s[t * NS + n];
    }
    size_t base = ((size_t)bi * DI + d) * NS;
    #pragma unroll
    for (int n = 0; n < NS; ++n) {
        hpart[base + n] = h[n];
        aprod[base + n] = __expf(asum * Ar[n]);
    }
}

// ---------------- K5b: propagate chunk-boundary states ----------------
__global__ __launch_bounds__(256) void k_mid(const float* __restrict__ aprod,
        const float* __restrict__ hpart, float* __restrict__ hin) {
    int g = blockIdx.x * 256 + threadIdx.x;   // B*K*DI*NS threads
    int bk = g / (DI * NS);
    int rem = g % (DI * NS);
    float h = 0.f;
    for (int c = 0; c < NCH; ++c) {
        size_t ix = ((size_t)(bk * NCH + c) * DI * NS) + rem;
        hin[ix] = h;
        h = aprod[ix] * h + hpart[ix];
    }
}

// ---------------- K5c: chunked scan pass 2 (full scan, emit y, atomic merge) ----------------
__global__ __launch_bounds__(192) void k_scan2(const float* __restrict__ xc,
        const float* __restrict__ dts_raw, const float* __restrict__ Bsg,
        const float* __restrict__ Csg, const float* __restrict__ A_logs,
        const float* __restrict__ dtw, const float* __restrict__ dtb,
        const float* __restrict__ hin, float* __restrict__ y0) {
    __shared__ float dts_s[LC * RR];
    __shared__ float bs_s[LC * NS];
    __shared__ float cs_s[LC * NS];
    int bi = blockIdx.x;
    int b = bi >> 7; int rem = bi & 127; int k = rem >> 5; int c0 = rem & 31;
    int t0 = c0 * LC;
    int d = threadIdx.x;
    size_t bkL = (size_t)(b * KK + k) * LL;
    for (int e = d; e < LC * RR; e += DI) dts_s[e] = dts_raw[(bkL + t0) * RR + e];
    for (int e = d; e < LC * NS; e += DI) bs_s[e] = Bsg[(bkL + t0) * NS + e];
    for (int e = d; e < LC * NS; e += DI) cs_s[e] = Csg[(bkL + t0) * NS + e];
    __syncthreads();
    int kd = k * DI + d;
    float Ar[NS];
    #pragma unroll
    for (int n = 0; n < NS; ++n) Ar[n] = -__expf(A_logs[(size_t)kd * NS + n]);
    float dw[RR];
    #pragma unroll
    for (int r = 0; r < RR; ++r) dw[r] = dtw[kd * RR + r];
    float bias = dtb[kd];
    size_t base = ((size_t)bi * DI + d) * NS;
    float h[NS];
    #pragma unroll
    for (int n = 0; n < NS; ++n) h[n] = hin[base + n];
    const float* xcb = xc + (size_t)b * LL * DI + d;
    float* y0b = y0 + (size_t)b * LL * DI + d;
    for (int t = 0; t < LC; ++t) {
        float dtr = bias;
        #pragma unroll
        for (int r = 0; r < RR; ++r) dtr += dts_s[t * RR + r] * dw[r];
        float dt = fsoftplus(dtr);
        int lx = lmap(k, t0 + t);
        float u = xcb[(size_t)lx * DI];
        float dtu = dt * u;
        float y = 0.f;
        #pragma unroll
        for (int n = 0; n < NS; ++n) {
            h[n] = h[n] * __expf(dt * Ar[n]) + dtu * bs_s[t * NS + n];
            y += h[n] * cs_s[t * NS + n];
        }
        atomicAdd(&y0b[(size_t)lx * DI], y);
    }
}

// ---------------- K6: LayerNorm + gate + out_proj (register-tiled GEMM) ----------------
// Block: 256 threads, 32 positions. Phase 1: 4 waves x 8 positions LN+gate -> gs LDS.
// Phase 2: thread = (pg = tid>>7, o = tid&127, active o<96); 16 position-accumulators,
// K marched in float4: Wout row from global (L2-resident), gs via broadcast ds_read_b128.
__global__ __launch_bounds__(256) void k_final(const float* __restrict__ y0,
        const float* __restrict__ zs, const float* __restrict__ nw,
        const float* __restrict__ nb, const float* __restrict__ Wout,
        float* __restrict__ out) {
    __shared__ __align__(16) float gs[32][DI];
    int tid = threadIdx.x;
    int wv = tid >> 6, lane = tid & 63;
    int Pbase = blockIdx.x * 32;
    // hoist per-lane norm params (same channels for every position)
    float nwv[3], nbv[3];
    #pragma unroll
    for (int j = 0; j < 3; ++j) { nwv[j] = nw[lane + 64 * j]; nbv[j] = nb[lane + 64 * j]; }
    // ---- phase 1: LayerNorm + silu-gate, 8 positions per wave ----
    for (int pi = 0; pi < 8; ++pi) {
        int pl = wv * 8 + pi;
        size_t Poff = (size_t)(Pbase + pl) * DI;
        float v[3];
        #pragma unroll
        for (int j = 0; j < 3; ++j) v[j] = y0[Poff + lane + 64 * j];
        float s = v[0] + v[1] + v[2];
        #pragma unroll
        for (int o = 32; o; o >>= 1) s += __shfl_xor(s, o);
        float mean = s * (1.f / 192.f);
        float ss = 0.f;
        #pragma unroll
        for (int j = 0; j < 3; ++j) { float dd = v[j] - mean; ss += dd * dd; }
        #pragma unroll
        for (int o = 32; o; o >>= 1) ss += __shfl_xor(ss, o);
        float rstd = rsqrtf(ss * (1.f / 192.f) + EPSN);
        #pragma unroll
        for (int j = 0; j < 3; ++j) {
            int c = lane + 64 * j;
            gs[pl][c] = ((v[j] - mean) * rstd * nwv[j] + nbv[j]) * zs[Poff + c];
        }
    }
    __syncthreads();
    // ---- phase 2: out = gs @ Wout^T ----
    int o = tid & 127;
    int pg = tid >> 7;          // 0 or 1 -> positions [pg*16, pg*16+16)
    if (o < DM) {
        const float* wr = Wout + (size_t)o * DI;
        float acc[16];
        #pragma unroll
        for (int p = 0; p < 16; ++p) acc[p] = 0.f;
        for (int k0 = 0; k0 < DI; k0 += 4) {
            float4 w4 = *(const float4*)(wr + k0);
            #pragma unroll
            for (int p = 0; p < 16; ++p) {
                float4 g4 = *(const float4*)(&gs[pg * 16 + p][k0]);
                acc[p] += w4.x * g4.x + w4.y * g4.y + w4.z * g4.z + w4.w * g4.w;
            }
        }
        #pragma unroll
        for (int p = 0; p < 16; ++p)
            out[(size_t)(Pbase + pg * 16 + p) * DM + o] = acc[p];
    }
}

extern "C" void kernel_launch(void* const* d_in, const int* in_sizes, int n_in,
                              void* d_out, int out_size, void* d_ws, size_t ws_size,
                              hipStream_t stream) {
    const float* x      = (const float*)d_in[0];
    const float* in_w   = (const float*)d_in[1];
    const float* conv_w = (const float*)d_in[2];
    const float* conv_b = (const float*)d_in[3];
    const float* xpw    = (const float*)d_in[4];
    const float* dtw    = (const float*)d_in[5];
    const float* A_logs = (const float*)d_in[6];
    const float* Ds     = (const float*)d_in[7];
    const float* dtb    = (const float*)d_in[8];
    const float* nw     = (const float*)d_in[9];
    const float* nb     = (const float*)d_in[10];
    const float* out_w  = (const float*)d_in[11];
    float* out = (float*)d_out;

    char* ws = (char*)d_ws;
    size_t off = 0;
    auto alloc = [&](size_t n) { float* p = (float*)(ws + off); off += n * sizeof(float); return p; };
    float* xx  = alloc((size_t)BB * LL * DI);
    float* zs  = alloc((size_t)BB * LL * DI);
    float* xc  = alloc((size_t)BB * LL * DI);
    float* y0  = alloc((size_t)BB * LL * DI);
    float* dts = alloc((size_t)BB * KK * LL * RR);
    float* Bsb = alloc((size_t)BB * KK * LL * NS);
    float* Csb = alloc((size_t)BB * KK * LL * NS);
    float* apr = alloc((size_t)BB * KK * NCH * DI * NS);
    float* hpp = alloc((size_t)BB * KK * NCH * DI * NS);
    float* hin = alloc((size_t)BB * KK * NCH * DI * NS);

    k_inproj<<<BB * LL / 8, 384, 0, stream>>>(x, in_w, xx, zs);
    k_conv<<<BB * LL * DI / 256, 256, 0, stream>>>(xx, conv_w, conv_b, Ds, xc, y0);
    k_xdbl<<<BB * LL / 64, 256, 0, stream>>>(xc, xpw, dts, Bsb, Csb);
    k_scan1<<<BB * KK * NCH, DI, 0, stream>>>(xc, dts, Bsb, A_logs, dtw, dtb, apr, hpp);
    k_mid<<<(BB * KK * DI * NS) / 256, 256, 0, stream>>>(apr, hpp, hin);
    k_scan2<<<BB * KK * NCH, DI, 0, stream>>>(xc, dts, Bsb, Csb, A_logs, dtw, dtb, hin, y0);
    k_final<<<BB * LL / 32, 256, 0, stream>>>(y0, zs, nw, nb, out_w, out);
}

// Round 5
// 785.876 us; speedup vs baseline: 1.3031x; 1.0153x over previous
//
#include <hip/hip_runtime.h>
#include <hip/hip_bf16.h>
#include <math.h>

#define BB 8
#define HS 64
#define WS 64
#define LL 4096
#define DM 96
#define DI 192
#define NS 16
#define RR 6
#define KK 4
#define NCH 64
#define LC 64
#define EPSN 1e-6f

__device__ __forceinline__ float fsilu(float x) { return x / (1.f + __expf(-x)); }
__device__ __forceinline__ float fsoftplus(float x) {
    return (x > 20.f) ? x : log1pf(__expf(x));
}
// spatial index l for direction k at scan step t (also equals inverse map)
__device__ __forceinline__ int lmap(int k, int t) {
    int tt = (k >= 2) ? (LL - 1 - t) : t;
    if (k & 1) tt = ((tt & 63) << 6) | (tt >> 6);
    return tt;
}

// ---------------- K1: in_proj + silu(z) ----------------
__global__ __launch_bounds__(384) void k_inproj(const float* __restrict__ x,
        const float* __restrict__ Win, float* __restrict__ xx, float* __restrict__ zs) {
    __shared__ float xrow[8][96];
    int p0 = blockIdx.x * 8;
    int tid = threadIdx.x;
    for (int e = tid; e < 8 * 96; e += 384) xrow[e / 96][e % 96] = x[(size_t)p0 * 96 + e];
    __syncthreads();
    const float* wr = Win + tid * 96;
    float acc[8] = {0.f, 0.f, 0.f, 0.f, 0.f, 0.f, 0.f, 0.f};
    #pragma unroll 4
    for (int kk = 0; kk < 96; ++kk) {
        float wv = wr[kk];
        #pragma unroll
        for (int p = 0; p < 8; ++p) acc[p] += wv * xrow[p][kk];
    }
    if (tid < DI) {
        #pragma unroll
        for (int p = 0; p < 8; ++p) xx[(size_t)(p0 + p) * DI + tid] = acc[p];
    } else {
        int d = tid - DI;
        #pragma unroll
        for (int p = 0; p < 8; ++p) zs[(size_t)(p0 + p) * DI + d] = fsilu(acc[p]);
    }
}

// ---------------- K2: depthwise conv 3x3 + silu + init y0 = xc * sum_k Ds ----------------
__global__ __launch_bounds__(256) void k_conv(const float* __restrict__ xx,
        const float* __restrict__ cw, const float* __restrict__ cb,
        const float* __restrict__ Ds, float* __restrict__ xc, float* __restrict__ y0) {
    int idx = blockIdx.x * 256 + threadIdx.x;   // = P*192 + d
    int d = idx % DI; int P = idx / DI;
    int l = P & (LL - 1); int h = l >> 6; int w = l & 63;
    float acc = cb[d];
    #pragma unroll
    for (int i = 0; i < 3; ++i) {
        int hh = h + i - 1;
        if ((unsigned)hh < 64u) {
            #pragma unroll
            for (int j = 0; j < 3; ++j) {
                int ww = w + j - 1;
                if ((unsigned)ww < 64u)
                    acc += xx[(size_t)(P + (i - 1) * 64 + (j - 1)) * DI + d] * cw[d * 9 + i * 3 + j];
            }
        }
    }
    float s = fsilu(acc);
    float sd = Ds[d] + Ds[DI + d] + Ds[2 * DI + d] + Ds[3 * DI + d];
    xc[idx] = s;
    y0[idx] = s * sd;
}

// ---------------- K3: x_dbl = xs @ xpw^T  -> dts_raw / Bs / Cs (scan order) ----------------
__global__ __launch_bounds__(256) void k_xdbl(const float* __restrict__ xc,
        const float* __restrict__ xpw, float* __restrict__ dts_raw,
        float* __restrict__ Bs, float* __restrict__ Cs) {
    __shared__ float xt[64][193];
    int tid = threadIdx.x;
    int p0 = blockIdx.x * 64;
    for (int e = tid; e < 64 * DI; e += 256) xt[e / DI][e % DI] = xc[(size_t)p0 * DI + e];
    __syncthreads();
    int p4 = tid >> 2, q = tid & 3;
    int P = p0 + p4;
    int b = P >> 12; int l = P & (LL - 1);
    int lt = ((l & 63) << 6) | (l >> 6);
    int tk[4] = { l, lt, LL - 1 - l, LL - 1 - lt };
    for (int c4 = 0; c4 < 38; ++c4) {
        float a0 = 0.f, a1 = 0.f, a2 = 0.f, a3 = 0.f;
        const float* w0 = xpw + (size_t)c4 * 4 * DI;
        #pragma unroll 8
        for (int i = 0; i < 48; ++i) {
            int j = i * 4 + q;
            float xv = xt[p4][j];
            a0 += xv * w0[j];
            a1 += xv * w0[DI + j];
            a2 += xv * w0[2 * DI + j];
            a3 += xv * w0[3 * DI + j];
        }
        float accs[4] = {a0, a1, a2, a3};
        #pragma unroll
        for (int cc = 0; cc < 4; ++cc) {
            float s = accs[cc];
            s += __shfl_xor(s, 1);
            s += __shfl_xor(s, 2);
            if (q == 0) {
                int c = c4 * 4 + cc;
                int k = c / 38, c2 = c % 38;
                size_t it = ((size_t)(b * KK + k) * LL + tk[k]);
                if (c2 < RR)            dts_raw[it * RR + c2] = s;
                else if (c2 < RR + NS)  Bs[it * NS + (c2 - RR)] = s;
                else                    Cs[it * NS + (c2 - RR - NS)] = s;
            }
        }
    }
}

// ---------------- K5a: chunked scan pass 1 (chunk summaries, h_in = 0) ----------------
__global__ __launch_bounds__(192) void k_scan1(const float* __restrict__ xc,
        const float* __restrict__ dts_raw, const float* __restrict__ Bsg,
        const float* __restrict__ A_logs, const float* __restrict__ dtw,
        const float* __restrict__ dtb,
        float* __restrict__ asum_g, float* __restrict__ hpart) {
    __shared__ __align__(16) float dts_s[LC * 8];
    __shared__ __align__(16) float bs_s[LC * NS];
    int bi = blockIdx.x;
    int b = bi >> 8; int rem = bi & 255; int k = rem >> 6; int c0 = rem & 63;
    int t0 = c0 * LC;
    int d = threadIdx.x;
    size_t g0 = (size_t)(b * KK + k) * LL + t0;
    for (int e = d; e < LC * RR; e += DI) dts_s[(e / RR) * 8 + (e % RR)] = dts_raw[g0 * RR + e];
    for (int e = d; e < LC * NS; e += DI) bs_s[e] = Bsg[g0 * NS + e];
    __syncthreads();
    int kd = k * DI + d;
    float Ar2[NS];
    #pragma unroll
    for (int n = 0; n < NS; ++n) Ar2[n] = -__expf(A_logs[(size_t)kd * NS + n]) * 1.44269504f;
    float dw[RR];
    #pragma unroll
    for (int r = 0; r < RR; ++r) dw[r] = dtw[kd * RR + r];
    float bias = dtb[kd];
    float h[NS];
    #pragma unroll
    for (int n = 0; n < NS; ++n) h[n] = 0.f;
    float asum = 0.f;
    const float* xcb = xc + (size_t)b * LL * DI + d;
    for (int tg = 0; tg < LC; tg += 4) {
        float uu[4];
        #pragma unroll
        for (int j = 0; j < 4; ++j) uu[j] = xcb[(size_t)lmap(k, t0 + tg + j) * DI];
        #pragma unroll
        for (int j = 0; j < 4; ++j) {
            int t = tg + j;
            float4 q4 = *(const float4*)&dts_s[t * 8];
            float2 q2 = *(const float2*)&dts_s[t * 8 + 4];
            float dtr = bias + q4.x * dw[0] + q4.y * dw[1] + q4.z * dw[2]
                             + q4.w * dw[3] + q2.x * dw[4] + q2.y * dw[5];
            float dt = fsoftplus(dtr);
            asum += dt;
            float dtu = dt * uu[j];
            #pragma unroll
            for (int n4 = 0; n4 < 4; ++n4) {
                float4 b4 = *(const float4*)&bs_s[t * NS + n4 * 4];
                h[n4*4+0] = h[n4*4+0] * exp2f(dt * Ar2[n4*4+0]) + dtu * b4.x;
                h[n4*4+1] = h[n4*4+1] * exp2f(dt * Ar2[n4*4+1]) + dtu * b4.y;
                h[n4*4+2] = h[n4*4+2] * exp2f(dt * Ar2[n4*4+2]) + dtu * b4.z;
                h[n4*4+3] = h[n4*4+3] * exp2f(dt * Ar2[n4*4+3]) + dtu * b4.w;
            }
        }
    }
    asum_g[(size_t)bi * DI + d] = asum;
    size_t base = ((size_t)bi * DI + d) * NS;
    #pragma unroll
    for (int n4 = 0; n4 < 4; ++n4) {
        float4 hv = make_float4(h[n4*4], h[n4*4+1], h[n4*4+2], h[n4*4+3]);
        *(float4*)&hpart[base + n4 * 4] = hv;
    }
}

// ---------------- K5b: propagate chunk-boundary states (in-place hpart -> hin) ----------------
__global__ __launch_bounds__(256) void k_mid(const float* __restrict__ asum_g,
        const float* __restrict__ A_logs, float* __restrict__ hpp) {
    int g = blockIdx.x * 256 + threadIdx.x;   // B*K*DI*NS threads
    int bk = g / (DI * NS);
    int rem = g % (DI * NS);
    int d = rem >> 4; int n = rem & 15;
    int k = bk & 3;
    float Ar2 = -__expf(A_logs[(size_t)(k * DI + d) * NS + n]) * 1.44269504f;
    float h = 0.f;
    for (int c = 0; c < NCH; ++c) {
        size_t row = (size_t)(bk * NCH + c) * DI + d;
        float a = exp2f(Ar2 * asum_g[row]);
        size_t ix = row * NS + n;
        float hp = hpp[ix];
        hpp[ix] = h;            // becomes hin for chunk c
        h = a * h + hp;
    }
}

// ---------------- K5c: chunked scan pass 2 (full scan, emit y, atomic merge) ----------------
__global__ __launch_bounds__(192) void k_scan2(const float* __restrict__ xc,
        const float* __restrict__ dts_raw, const float* __restrict__ Bsg,
        const float* __restrict__ Csg, const float* __restrict__ A_logs,
        const float* __restrict__ dtw, const float* __restrict__ dtb,
        const float* __restrict__ hinb, float* __restrict__ y0) {
    __shared__ __align__(16) float dts_s[LC * 8];
    __shared__ __align__(16) float bs_s[LC * NS];
    __shared__ __align__(16) float cs_s[LC * NS];
    int bi = blockIdx.x;
    int b = bi >> 8; int rem = bi & 255; int k = rem >> 6; int c0 = rem & 63;
    int t0 = c0 * LC;
    int d = threadIdx.x;
    size_t g0 = (size_t)(b * KK + k) * LL + t0;
    for (int e = d; e < LC * RR; e += DI) dts_s[(e / RR) * 8 + (e % RR)] = dts_raw[g0 * RR + e];
    for (int e = d; e < LC * NS; e += DI) bs_s[e] = Bsg[g0 * NS + e];
    for (int e = d; e < LC * NS; e += DI) cs_s[e] = Csg[g0 * NS + e];
    __syncthreads();
    int kd = k * DI + d;
    float Ar2[NS];
    #pragma unroll
    for (int n = 0; n < NS; ++n) Ar2[n] = -__expf(A_logs[(size_t)kd * NS + n]) * 1.44269504f;
    float dw[RR];
    #pragma unroll
    for (int r = 0; r < RR; ++r) dw[r] = dtw[kd * RR + r];
    float bias = dtb[kd];
    size_t base = ((size_t)bi * DI + d) * NS;
    float h[NS];
    #pragma unroll
    for (int n4 = 0; n4 < 4; ++n4) {
        float4 hv = *(const float4*)&hinb[base + n4 * 4];
        h[n4*4+0] = hv.x; h[n4*4+1] = hv.y; h[n4*4+2] = hv.z; h[n4*4+3] = hv.w;
    }
    const float* xcb = xc + (size_t)b * LL * DI + d;
    float* y0b = y0 + (size_t)b * LL * DI + d;
    for (int tg = 0; tg < LC; tg += 4) {
        float uu[4];
        int lx[4];
        #pragma unroll
        for (int j = 0; j < 4; ++j) {
            lx[j] = lmap(k, t0 + tg + j);
            uu[j] = xcb[(size_t)lx[j] * DI];
        }
        #pragma unroll
        for (int j = 0; j < 4; ++j) {
            int t = tg + j;
            float4 q4 = *(const float4*)&dts_s[t * 8];
            float2 q2 = *(const float2*)&dts_s[t * 8 + 4];
            float dtr = bias + q4.x * dw[0] + q4.y * dw[1] + q4.z * dw[2]
                             + q4.w * dw[3] + q2.x * dw[4] + q2.y * dw[5];
            float dt = fsoftplus(dtr);
            float dtu = dt * uu[j];
            float y = 0.f;
            #pragma unroll
            for (int n4 = 0; n4 < 4; ++n4) {
                float4 b4 = *(const float4*)&bs_s[t * NS + n4 * 4];
                float4 c4 = *(const float4*)&cs_s[t * NS + n4 * 4];
                h[n4*4+0] = h[n4*4+0] * exp2f(dt * Ar2[n4*4+0]) + dtu * b4.x;
                h[n4*4+1] = h[n4*4+1] * exp2f(dt * Ar2[n4*4+1]) + dtu * b4.y;
                h[n4*4+2] = h[n4*4+2] * exp2f(dt * Ar2[n4*4+2]) + dtu * b4.z;
                h[n4*4+3] = h[n4*4+3] * exp2f(dt * Ar2[n4*4+3]) + dtu * b4.w;
                y += h[n4*4+0] * c4.x + h[n4*4+1] * c4.y + h[n4*4+2] * c4.z + h[n4*4+3] * c4.w;
            }
            atomicAdd(&y0b[(size_t)lx[j] * DI], y);
        }
    }
}

// ---------------- K6: LayerNorm + gate + out_proj (register-tiled GEMM) ----------------
__global__ __launch_bounds__(256) void k_final(const float* __restrict__ y0,
        const float* __restrict__ zs, const float* __restrict__ nw,
        const float* __restrict__ nb, const float* __restrict__ Wout,
        float* __restrict__ out) {
    __shared__ __align__(16) float gs[32][DI];
    int tid = threadIdx.x;
    int wv = tid >> 6, lane = tid & 63;
    int Pbase = blockIdx.x * 32;
    float nwv[3], nbv[3];
    #pragma unroll
    for (int j = 0; j < 3; ++j) { nwv[j] = nw[lane + 64 * j]; nbv[j] = nb[lane + 64 * j]; }
    for (int pi = 0; pi < 8; ++pi) {
        int pl = wv * 8 + pi;
        size_t Poff = (size_t)(Pbase + pl) * DI;
        float v[3];
        #pragma unroll
        for (int j = 0; j < 3; ++j) v[j] = y0[Poff + lane + 64 * j];
        float s = v[0] + v[1] + v[2];
        #pragma unroll
        for (int o = 32; o; o >>= 1) s += __shfl_xor(s, o);
        float mean = s * (1.f / 192.f);
        float ss = 0.f;
        #pragma unroll
        for (int j = 0; j < 3; ++j) { float dd = v[j] - mean; ss += dd * dd; }
        #pragma unroll
        for (int o = 32; o; o >>= 1) ss += __shfl_xor(ss, o);
        float rstd = rsqrtf(ss * (1.f / 192.f) + EPSN);
        #pragma unroll
        for (int j = 0; j < 3; ++j) {
            int c = lane + 64 * j;
            gs[pl][c] = ((v[j] - mean) * rstd * nwv[j] + nbv[j]) * zs[Poff + c];
        }
    }
    __syncthreads();
    int o = tid & 127;
    int pg = tid >> 7;
    if (o < DM) {
        const float* wr = Wout + (size_t)o * DI;
        float acc[16];
        #pragma unroll
        for (int p = 0; p < 16; ++p) acc[p] = 0.f;
        for (int k0 = 0; k0 < DI; k0 += 4) {
            float4 w4 = *(const float4*)(wr + k0);
            #pragma unroll
            for (int p = 0; p < 16; ++p) {
                float4 g4 = *(const float4*)(&gs[pg * 16 + p][k0]);
                acc[p] += w4.x * g4.x + w4.y * g4.y + w4.z * g4.z + w4.w * g4.w;
            }
        }
        #pragma unroll
        for (int p = 0; p < 16; ++p)
            out[(size_t)(Pbase + pg * 16 + p) * DM + o] = acc[p];
    }
}

extern "C" void kernel_launch(void* const* d_in, const int* in_sizes, int n_in,
                              void* d_out, int out_size, void* d_ws, size_t ws_size,
                              hipStream_t stream) {
    const float* x      = (const float*)d_in[0];
    const float* in_w   = (const float*)d_in[1];
    const float* conv_w = (const float*)d_in[2];
    const float* conv_b = (const float*)d_in[3];
    const float* xpw    = (const float*)d_in[4];
    const float* dtw    = (const float*)d_in[5];
    const float* A_logs = (const float*)d_in[6];
    const float* Ds     = (const float*)d_in[7];
    const float* dtb    = (const float*)d_in[8];
    const float* nw     = (const float*)d_in[9];
    const float* nb     = (const float*)d_in[10];
    const float* out_w  = (const float*)d_in[11];
    float* out = (float*)d_out;

    char* ws = (char*)d_ws;
    size_t off = 0;
    auto alloc = [&](size_t n) { float* p = (float*)(ws + off); off += n * sizeof(float); return p; };
    float* xx   = alloc((size_t)BB * LL * DI);
    float* zs   = alloc((size_t)BB * LL * DI);
    float* xc   = alloc((size_t)BB * LL * DI);
    float* y0   = alloc((size_t)BB * LL * DI);
    float* dts  = alloc((size_t)BB * KK * LL * RR);
    float* Bsb  = alloc((size_t)BB * KK * LL * NS);
    float* Csb  = alloc((size_t)BB * KK * LL * NS);
    float* asum = alloc((size_t)BB * KK * NCH * DI);
    float* hpp  = alloc((size_t)BB * KK * NCH * DI * NS);

    k_inproj<<<BB * LL / 8, 384, 0, stream>>>(x, in_w, xx, zs);
    k_conv<<<BB * LL * DI / 256, 256, 0, stream>>>(xx, conv_w, conv_b, Ds, xc, y0);
    k_xdbl<<<BB * LL / 64, 256, 0, stream>>>(xc, xpw, dts, Bsb, Csb);
    k_scan1<<<BB * KK * NCH, DI, 0, stream>>>(xc, dts, Bsb, A_logs, dtw, dtb, asum, hpp);
    k_mid<<<(BB * KK * DI * NS) / 256, 256, 0, stream>>>(asum, A_logs, hpp);
    k_scan2<<<BB * KK * NCH, DI, 0, stream>>>(xc, dts, Bsb, Csb, A_logs, dtw, dtb, hpp, y0);
    k_final<<<BB * LL / 32, 256, 0, stream>>>(y0, zs, nw, nb, out_w, out);
}

// Round 6
// 552.523 us; speedup vs baseline: 1.8535x; 1.4223x over previous
//
#include <hip/hip_runtime.h>
#include <hip/hip_bf16.h>
#include <math.h>

#define BB 8
#define HS 64
#define WS 64
#define LL 4096
#define DM 96
#define DI 192
#define NS 16
#define RR 6
#define KK 4
#define NCH 64
#define LC 64
#define EPSN 1e-6f

__device__ __forceinline__ float fsilu(float x) { return x / (1.f + __expf(-x)); }
// raw hardware transcendentals: v_exp_f32 computes 2^x, v_log_f32 computes log2(x)
__device__ __forceinline__ float rexp2(float x) {
    float r; asm("v_exp_f32 %0, %1" : "=v"(r) : "v"(x)); return r;
}
__device__ __forceinline__ float rlog2(float x) {
    float r; asm("v_log_f32 %0, %1" : "=v"(r) : "v"(x)); return r;
}
// softplus(x) = ln(1+e^x) = ln2 * log2(1 + 2^(x*log2e)); ~6 instrs vs libm's ~40
__device__ __forceinline__ float fsoftplus(float x) {
    float t = rexp2(x * 1.44269504f);
    float r = 0.69314718f * rlog2(1.f + t);
    return (x > 20.f) ? x : r;
}
// spatial index l for direction k at scan step t (also equals inverse map)
__device__ __forceinline__ int lmap(int k, int t) {
    int tt = (k >= 2) ? (LL - 1 - t) : t;
    if (k & 1) tt = ((tt & 63) << 6) | (tt >> 6);
    return tt;
}

// ---------------- K1: in_proj + silu(z) ----------------
__global__ __launch_bounds__(384) void k_inproj(const float* __restrict__ x,
        const float* __restrict__ Win, float* __restrict__ xx, float* __restrict__ zs) {
    __shared__ float xrow[8][96];
    int p0 = blockIdx.x * 8;
    int tid = threadIdx.x;
    for (int e = tid; e < 8 * 96; e += 384) xrow[e / 96][e % 96] = x[(size_t)p0 * 96 + e];
    __syncthreads();
    const float* wr = Win + tid * 96;
    float acc[8] = {0.f, 0.f, 0.f, 0.f, 0.f, 0.f, 0.f, 0.f};
    #pragma unroll 4
    for (int kk = 0; kk < 96; ++kk) {
        float wv = wr[kk];
        #pragma unroll
        for (int p = 0; p < 8; ++p) acc[p] += wv * xrow[p][kk];
    }
    if (tid < DI) {
        #pragma unroll
        for (int p = 0; p < 8; ++p) xx[(size_t)(p0 + p) * DI + tid] = acc[p];
    } else {
        int d = tid - DI;
        #pragma unroll
        for (int p = 0; p < 8; ++p) zs[(size_t)(p0 + p) * DI + d] = fsilu(acc[p]);
    }
}

// ---------------- K2: depthwise conv 3x3 + silu + init y0 = xc * sum_k Ds ----------------
__global__ __launch_bounds__(256) void k_conv(const float* __restrict__ xx,
        const float* __restrict__ cw, const float* __restrict__ cb,
        const float* __restrict__ Ds, float* __restrict__ xc, float* __restrict__ y0) {
    int idx = blockIdx.x * 256 + threadIdx.x;   // = P*192 + d
    int d = idx % DI; int P = idx / DI;
    int l = P & (LL - 1); int h = l >> 6; int w = l & 63;
    float acc = cb[d];
    #pragma unroll
    for (int i = 0; i < 3; ++i) {
        int hh = h + i - 1;
        if ((unsigned)hh < 64u) {
            #pragma unroll
            for (int j = 0; j < 3; ++j) {
                int ww = w + j - 1;
                if ((unsigned)ww < 64u)
                    acc += xx[(size_t)(P + (i - 1) * 64 + (j - 1)) * DI + d] * cw[d * 9 + i * 3 + j];
            }
        }
    }
    float s = fsilu(acc);
    float sd = Ds[d] + Ds[DI + d] + Ds[2 * DI + d] + Ds[3 * DI + d];
    xc[idx] = s;
    y0[idx] = s * sd;
}

// ---------------- K3: x_dbl = xs @ xpw^T  -> dts_raw / Bs / Cs (scan order) ----------------
__global__ __launch_bounds__(256) void k_xdbl(const float* __restrict__ xc,
        const float* __restrict__ xpw, float* __restrict__ dts_raw,
        float* __restrict__ Bs, float* __restrict__ Cs) {
    __shared__ float xt[64][193];
    int tid = threadIdx.x;
    int p0 = blockIdx.x * 64;
    for (int e = tid; e < 64 * DI; e += 256) xt[e / DI][e % DI] = xc[(size_t)p0 * DI + e];
    __syncthreads();
    int p4 = tid >> 2, q = tid & 3;
    int P = p0 + p4;
    int b = P >> 12; int l = P & (LL - 1);
    int lt = ((l & 63) << 6) | (l >> 6);
    int tk[4] = { l, lt, LL - 1 - l, LL - 1 - lt };
    for (int c4 = 0; c4 < 38; ++c4) {
        float a0 = 0.f, a1 = 0.f, a2 = 0.f, a3 = 0.f;
        const float* w0 = xpw + (size_t)c4 * 4 * DI;
        #pragma unroll 8
        for (int i = 0; i < 48; ++i) {
            int j = i * 4 + q;
            float xv = xt[p4][j];
            a0 += xv * w0[j];
            a1 += xv * w0[DI + j];
            a2 += xv * w0[2 * DI + j];
            a3 += xv * w0[3 * DI + j];
        }
        float accs[4] = {a0, a1, a2, a3};
        #pragma unroll
        for (int cc = 0; cc < 4; ++cc) {
            float s = accs[cc];
            s += __shfl_xor(s, 1);
            s += __shfl_xor(s, 2);
            if (q == 0) {
                int c = c4 * 4 + cc;
                int k = c / 38, c2 = c % 38;
                size_t it = ((size_t)(b * KK + k) * LL + tk[k]);
                if (c2 < RR)            dts_raw[it * RR + c2] = s;
                else if (c2 < RR + NS)  Bs[it * NS + (c2 - RR)] = s;
                else                    Cs[it * NS + (c2 - RR - NS)] = s;
            }
        }
    }
}

// ---------------- K5a: chunked scan pass 1 (chunk summaries, h_in = 0) ----------------
__global__ __launch_bounds__(192) void k_scan1(const float* __restrict__ xc,
        const float* __restrict__ dts_raw, const float* __restrict__ Bsg,
        const float* __restrict__ A_logs, const float* __restrict__ dtw,
        const float* __restrict__ dtb,
        float* __restrict__ asum_g, float* __restrict__ hpart) {
    __shared__ __align__(16) float dts_s[LC * 8];
    __shared__ __align__(16) float bs_s[LC * NS];
    int bi = blockIdx.x;
    int b = bi >> 8; int rem = bi & 255; int k = rem >> 6; int c0 = rem & 63;
    int t0 = c0 * LC;
    int d = threadIdx.x;
    size_t g0 = (size_t)(b * KK + k) * LL + t0;
    for (int e = d; e < LC * RR; e += DI) dts_s[(e / RR) * 8 + (e % RR)] = dts_raw[g0 * RR + e];
    for (int e = d; e < LC * NS; e += DI) bs_s[e] = Bsg[g0 * NS + e];
    __syncthreads();
    int kd = k * DI + d;
    float Ar2[NS];
    #pragma unroll
    for (int n = 0; n < NS; ++n) Ar2[n] = -__expf(A_logs[(size_t)kd * NS + n]) * 1.44269504f;
    float dw[RR];
    #pragma unroll
    for (int r = 0; r < RR; ++r) dw[r] = dtw[kd * RR + r];
    float bias = dtb[kd];
    float h[NS];
    #pragma unroll
    for (int n = 0; n < NS; ++n) h[n] = 0.f;
    float asum = 0.f;
    const float* xcb = xc + (size_t)b * LL * DI + d;
    for (int tg = 0; tg < LC; tg += 4) {
        float uu[4];
        #pragma unroll
        for (int j = 0; j < 4; ++j) uu[j] = xcb[(size_t)lmap(k, t0 + tg + j) * DI];
        #pragma unroll
        for (int j = 0; j < 4; ++j) {
            int t = tg + j;
            float4 q4 = *(const float4*)&dts_s[t * 8];
            float2 q2 = *(const float2*)&dts_s[t * 8 + 4];
            float dtr = bias + q4.x * dw[0] + q4.y * dw[1] + q4.z * dw[2]
                             + q4.w * dw[3] + q2.x * dw[4] + q2.y * dw[5];
            float dt = fsoftplus(dtr);
            asum += dt;
            float dtu = dt * uu[j];
            #pragma unroll
            for (int n4 = 0; n4 < 4; ++n4) {
                float4 b4 = *(const float4*)&bs_s[t * NS + n4 * 4];
                h[n4*4+0] = h[n4*4+0] * rexp2(dt * Ar2[n4*4+0]) + dtu * b4.x;
                h[n4*4+1] = h[n4*4+1] * rexp2(dt * Ar2[n4*4+1]) + dtu * b4.y;
                h[n4*4+2] = h[n4*4+2] * rexp2(dt * Ar2[n4*4+2]) + dtu * b4.z;
                h[n4*4+3] = h[n4*4+3] * rexp2(dt * Ar2[n4*4+3]) + dtu * b4.w;
            }
        }
    }
    asum_g[(size_t)bi * DI + d] = asum;
    size_t base = ((size_t)bi * DI + d) * NS;
    #pragma unroll
    for (int n4 = 0; n4 < 4; ++n4) {
        float4 hv = make_float4(h[n4*4], h[n4*4+1], h[n4*4+2], h[n4*4+3]);
        *(float4*)&hpart[base + n4 * 4] = hv;
    }
}

// ---------------- K5b: propagate chunk-boundary states (in-place hpart -> hin) ----------------
__global__ __launch_bounds__(256) void k_mid(const float* __restrict__ asum_g,
        const float* __restrict__ A_logs, float* __restrict__ hpp) {
    int g = blockIdx.x * 256 + threadIdx.x;   // B*K*DI*NS threads
    int bk = g / (DI * NS);
    int rem = g % (DI * NS);
    int d = rem >> 4; int n = rem & 15;
    int k = bk & 3;
    float Ar2 = -__expf(A_logs[(size_t)(k * DI + d) * NS + n]) * 1.44269504f;
    float h = 0.f;
    for (int c = 0; c < NCH; ++c) {
        size_t row = (size_t)(bk * NCH + c) * DI + d;
        float a = rexp2(Ar2 * asum_g[row]);
        size_t ix = row * NS + n;
        float hp = hpp[ix];
        hpp[ix] = h;            // becomes hin for chunk c
        h = a * h + hp;
    }
}

// ---------------- K5c: chunked scan pass 2 (full scan, emit y, atomic merge) ----------------
__global__ __launch_bounds__(192) void k_scan2(const float* __restrict__ xc,
        const float* __restrict__ dts_raw, const float* __restrict__ Bsg,
        const float* __restrict__ Csg, const float* __restrict__ A_logs,
        const float* __restrict__ dtw, const float* __restrict__ dtb,
        const float* __restrict__ hinb, float* __restrict__ y0) {
    __shared__ __align__(16) float dts_s[LC * 8];
    __shared__ __align__(16) float bs_s[LC * NS];
    __shared__ __align__(16) float cs_s[LC * NS];
    int bi = blockIdx.x;
    int b = bi >> 8; int rem = bi & 255; int k = rem >> 6; int c0 = rem & 63;
    int t0 = c0 * LC;
    int d = threadIdx.x;
    size_t g0 = (size_t)(b * KK + k) * LL + t0;
    for (int e = d; e < LC * RR; e += DI) dts_s[(e / RR) * 8 + (e % RR)] = dts_raw[g0 * RR + e];
    for (int e = d; e < LC * NS; e += DI) bs_s[e] = Bsg[g0 * NS + e];
    for (int e = d; e < LC * NS; e += DI) cs_s[e] = Csg[g0 * NS + e];
    __syncthreads();
    int kd = k * DI + d;
    float Ar2[NS];
    #pragma unroll
    for (int n = 0; n < NS; ++n) Ar2[n] = -__expf(A_logs[(size_t)kd * NS + n]) * 1.44269504f;
    float dw[RR];
    #pragma unroll
    for (int r = 0; r < RR; ++r) dw[r] = dtw[kd * RR + r];
    float bias = dtb[kd];
    size_t base = ((size_t)bi * DI + d) * NS;
    float h[NS];
    #pragma unroll
    for (int n4 = 0; n4 < 4; ++n4) {
        float4 hv = *(const float4*)&hinb[base + n4 * 4];
        h[n4*4+0] = hv.x; h[n4*4+1] = hv.y; h[n4*4+2] = hv.z; h[n4*4+3] = hv.w;
    }
    const float* xcb = xc + (size_t)b * LL * DI + d;
    float* y0b = y0 + (size_t)b * LL * DI + d;
    for (int tg = 0; tg < LC; tg += 4) {
        float uu[4];
        int lx[4];
        #pragma unroll
        for (int j = 0; j < 4; ++j) {
            lx[j] = lmap(k, t0 + tg + j);
            uu[j] = xcb[(size_t)lx[j] * DI];
        }
        #pragma unroll
        for (int j = 0; j < 4; ++j) {
            int t = tg + j;
            float4 q4 = *(const float4*)&dts_s[t * 8];
            float2 q2 = *(const float2*)&dts_s[t * 8 + 4];
            float dtr = bias + q4.x * dw[0] + q4.y * dw[1] + q4.z * dw[2]
                             + q4.w * dw[3] + q2.x * dw[4] + q2.y * dw[5];
            float dt = fsoftplus(dtr);
            float dtu = dt * uu[j];
            float y = 0.f;
            #pragma unroll
            for (int n4 = 0; n4 < 4; ++n4) {
                float4 b4 = *(const float4*)&bs_s[t * NS + n4 * 4];
                float4 c4 = *(const float4*)&cs_s[t * NS + n4 * 4];
                h[n4*4+0] = h[n4*4+0] * rexp2(dt * Ar2[n4*4+0]) + dtu * b4.x;
                h[n4*4+1] = h[n4*4+1] * rexp2(dt * Ar2[n4*4+1]) + dtu * b4.y;
                h[n4*4+2] = h[n4*4+2] * rexp2(dt * Ar2[n4*4+2]) + dtu * b4.z;
                h[n4*4+3] = h[n4*4+3] * rexp2(dt * Ar2[n4*4+3]) + dtu * b4.w;
                y += h[n4*4+0] * c4.x + h[n4*4+1] * c4.y + h[n4*4+2] * c4.z + h[n4*4+3] * c4.w;
            }
            atomicAdd(&y0b[(size_t)lx[j] * DI], y);
        }
    }
}

// ---------------- K6: LayerNorm + gate + out_proj (register-tiled GEMM) ----------------
__global__ __launch_bounds__(256) void k_final(const float* __restrict__ y0,
        const float* __restrict__ zs, const float* __restrict__ nw,
        const float* __restrict__ nb, const float* __restrict__ Wout,
        float* __restrict__ out) {
    __shared__ __align__(16) float gs[32][DI];
    int tid = threadIdx.x;
    int wv = tid >> 6, lane = tid & 63;
    int Pbase = blockIdx.x * 32;
    float nwv[3], nbv[3];
    #pragma unroll
    for (int j = 0; j < 3; ++j) { nwv[j] = nw[lane + 64 * j]; nbv[j] = nb[lane + 64 * j]; }
    for (int pi = 0; pi < 8; ++pi) {
        int pl = wv * 8 + pi;
        size_t Poff = (size_t)(Pbase + pl) * DI;
        float v[3];
        #pragma unroll
        for (int j = 0; j < 3; ++j) v[j] = y0[Poff + lane + 64 * j];
        float s = v[0] + v[1] + v[2];
        #pragma unroll
        for (int o = 32; o; o >>= 1) s += __shfl_xor(s, o);
        float mean = s * (1.f / 192.f);
        float ss = 0.f;
        #pragma unroll
        for (int j = 0; j < 3; ++j) { float dd = v[j] - mean; ss += dd * dd; }
        #pragma unroll
        for (int o = 32; o; o >>= 1) ss += __shfl_xor(ss, o);
        float rstd = rsqrtf(ss * (1.f / 192.f) + EPSN);
        #pragma unroll
        for (int j = 0; j < 3; ++j) {
            int c = lane + 64 * j;
            gs[pl][c] = ((v[j] - mean) * rstd * nwv[j] + nbv[j]) * zs[Poff + c];
        }
    }
    __syncthreads();
    int o = tid & 127;
    int pg = tid >> 7;
    if (o < DM) {
        const float* wr = Wout + (size_t)o * DI;
        float acc[16];
        #pragma unroll
        for (int p = 0; p < 16; ++p) acc[p] = 0.f;
        for (int k0 = 0; k0 < DI; k0 += 4) {
            float4 w4 = *(const float4*)(wr + k0);
            #pragma unroll
            for (int p = 0; p < 16; ++p) {
                float4 g4 = *(const float4*)(&gs[pg * 16 + p][k0]);
                acc[p] += w4.x * g4.x + w4.y * g4.y + w4.z * g4.z + w4.w * g4.w;
            }
        }
        #pragma unroll
        for (int p = 0; p < 16; ++p)
            out[(size_t)(Pbase + pg * 16 + p) * DM + o] = acc[p];
    }
}

extern "C" void kernel_launch(void* const* d_in, const int* in_sizes, int n_in,
                              void* d_out, int out_size, void* d_ws, size_t ws_size,
                              hipStream_t stream) {
    const float* x      = (const float*)d_in[0];
    const float* in_w   = (const float*)d_in[1];
    const float* conv_w = (const float*)d_in[2];
    const float* conv_b = (const float*)d_in[3];
    const float* xpw    = (const float*)d_in[4];
    const float* dtw    = (const float*)d_in[5];
    const float* A_logs = (const float*)d_in[6];
    const float* Ds     = (const float*)d_in[7];
    const float* dtb    = (const float*)d_in[8];
    const float* nw     = (const float*)d_in[9];
    const float* nb     = (const float*)d_in[10];
    const float* out_w  = (const float*)d_in[11];
    float* out = (float*)d_out;

    char* ws = (char*)d_ws;
    size_t off = 0;
    auto alloc = [&](size_t n) { float* p = (float*)(ws + off); off += n * sizeof(float); return p; };
    float* xx   = alloc((size_t)BB * LL * DI);
    float* zs   = alloc((size_t)BB * LL * DI);
    float* xc   = alloc((size_t)BB * LL * DI);
    float* y0   = alloc((size_t)BB * LL * DI);
    float* dts  = alloc((size_t)BB * KK * LL * RR);
    float* Bsb  = alloc((size_t)BB * KK * LL * NS);
    float* Csb  = alloc((size_t)BB * KK * LL * NS);
    float* asum = alloc((size_t)BB * KK * NCH * DI);
    float* hpp  = alloc((size_t)BB * KK * NCH * DI * NS);

    k_inproj<<<BB * LL / 8, 384, 0, stream>>>(x, in_w, xx, zs);
    k_conv<<<BB * LL * DI / 256, 256, 0, stream>>>(xx, conv_w, conv_b, Ds, xc, y0);
    k_xdbl<<<BB * LL / 64, 256, 0, stream>>>(xc, xpw, dts, Bsb, Csb);
    k_scan1<<<BB * KK * NCH, DI, 0, stream>>>(xc, dts, Bsb, A_logs, dtw, dtb, asum, hpp);
    k_mid<<<(BB * KK * DI * NS) / 256, 256, 0, stream>>>(asum, A_logs, hpp);
    k_scan2<<<BB * KK * NCH, DI, 0, stream>>>(xc, dts, Bsb, Csb, A_logs, dtw, dtb, hpp, y0);
    k_final<<<BB * LL / 32, 256, 0, stream>>>(y0, zs, nw, nb, out_w, out);
}

// Round 7
// 431.883 us; speedup vs baseline: 2.3712x; 1.2793x over previous
//
#include <hip/hip_runtime.h>
#include <hip/hip_bf16.h>
#include <math.h>

#define BB 8
#define HS 64
#define WS 64
#define LL 4096
#define DM 96
#define DI 192
#define NS 16
#define RR 6
#define KK 4
#define NCH 64
#define LC 64
#define XP 16
#define EPSN 1e-6f

__device__ __forceinline__ float fsilu(float x) { return x / (1.f + __expf(-x)); }
// raw hardware transcendentals: v_exp_f32 computes 2^x, v_log_f32 computes log2(x)
__device__ __forceinline__ float rexp2(float x) {
    float r; asm("v_exp_f32 %0, %1" : "=v"(r) : "v"(x)); return r;
}
__device__ __forceinline__ float rlog2(float x) {
    float r; asm("v_log_f32 %0, %1" : "=v"(r) : "v"(x)); return r;
}
// softplus(x) = ln(1+e^x) = ln2 * log2(1 + 2^(x*log2e))
__device__ __forceinline__ float fsoftplus(float x) {
    float t = rexp2(x * 1.44269504f);
    float r = 0.69314718f * rlog2(1.f + t);
    return (x > 20.f) ? x : r;
}
// spatial index l for direction k at scan step t (also equals inverse map)
__device__ __forceinline__ int lmap(int k, int t) {
    int tt = (k >= 2) ? (LL - 1 - t) : t;
    if (k & 1) tt = ((tt & 63) << 6) | (tt >> 6);
    return tt;
}

// ---------------- K1: in_proj + silu(z) ----------------
__global__ __launch_bounds__(384) void k_inproj(const float* __restrict__ x,
        const float* __restrict__ Win, float* __restrict__ xx, float* __restrict__ zs) {
    __shared__ __align__(16) float xrow[8][96];
    int p0 = blockIdx.x * 8;
    int tid = threadIdx.x;
    {   // vectorized x staging: 8*96/4 = 192 float4
        const float4* src = (const float4*)(x + (size_t)p0 * 96);
        float4* dst = (float4*)&xrow[0][0];
        if (tid < 192) dst[tid] = src[tid];
    }
    __syncthreads();
    const float4* wr4 = (const float4*)(Win + (size_t)tid * 96);
    float acc[8] = {0.f, 0.f, 0.f, 0.f, 0.f, 0.f, 0.f, 0.f};
    #pragma unroll 6
    for (int i = 0; i < 24; ++i) {
        float4 w4 = wr4[i];
        #pragma unroll
        for (int p = 0; p < 8; ++p) {
            float4 x4 = *(const float4*)&xrow[p][i * 4];
            acc[p] += w4.x * x4.x + w4.y * x4.y + w4.z * x4.z + w4.w * x4.w;
        }
    }
    if (tid < DI) {
        #pragma unroll
        for (int p = 0; p < 8; ++p) xx[(size_t)(p0 + p) * DI + tid] = acc[p];
    } else {
        int d = tid - DI;
        #pragma unroll
        for (int p = 0; p < 8; ++p) zs[(size_t)(p0 + p) * DI + d] = fsilu(acc[p]);
    }
}

// ---------------- K2: depthwise conv 3x3 + silu + init y0 = xc * sum_k Ds ----------------
__global__ __launch_bounds__(256) void k_conv(const float* __restrict__ xx,
        const float* __restrict__ cw, const float* __restrict__ cb,
        const float* __restrict__ Ds, float* __restrict__ xc, float* __restrict__ y0) {
    int idx = blockIdx.x * 256 + threadIdx.x;   // = P*192 + d
    int d = idx % DI; int P = idx / DI;
    int l = P & (LL - 1); int h = l >> 6; int w = l & 63;
    float acc = cb[d];
    #pragma unroll
    for (int i = 0; i < 3; ++i) {
        int hh = h + i - 1;
        if ((unsigned)hh < 64u) {
            #pragma unroll
            for (int j = 0; j < 3; ++j) {
                int ww = w + j - 1;
                if ((unsigned)ww < 64u)
                    acc += xx[(size_t)(P + (i - 1) * 64 + (j - 1)) * DI + d] * cw[d * 9 + i * 3 + j];
            }
        }
    }
    float s = fsilu(acc);
    float sd = Ds[d] + Ds[DI + d] + Ds[2 * DI + d] + Ds[3 * DI + d];
    xc[idx] = s;
    y0[idx] = s * sd;
}

// ---------------- K3: x_dbl = xs @ xpw^T  -> dts_raw / Bs / Cs (scan order) ----------------
// Thread = output channel c (152 active of 192); 16 positions/block; weight row via
// float4 from L2; x rows via broadcast ds_read_b128 (no bank conflicts).
__global__ __launch_bounds__(192) void k_xdbl(const float* __restrict__ xc,
        const float* __restrict__ xpw, float* __restrict__ dts_raw,
        float* __restrict__ Bs, float* __restrict__ Cs) {
    __shared__ __align__(16) float xt[XP][DI];
    int tid = threadIdx.x;
    int p0 = blockIdx.x * XP;
    {   // stage 16*192 floats = 768 float4 by 192 threads (4 each)
        const float4* src = (const float4*)(xc + (size_t)p0 * DI);
        float4* dst = (float4*)&xt[0][0];
        #pragma unroll
        for (int e = 0; e < XP * DI / 4 / 192; ++e) dst[tid + e * 192] = src[tid + e * 192];
    }
    __syncthreads();
    int c = tid;                 // output channel slot
    int k = c / 38, c2 = c % 38; // valid for c < 152
    const float4* w4p = (const float4*)(xpw + (size_t)c * DI);
    float acc[XP];
    #pragma unroll
    for (int p = 0; p < XP; ++p) acc[p] = 0.f;
    if (c < 152) {
        #pragma unroll 4
        for (int i = 0; i < DI / 4; ++i) {
            float4 w4 = w4p[i];
            #pragma unroll
            for (int p = 0; p < XP; ++p) {
                float4 x4 = *(const float4*)&xt[p][i * 4];
                acc[p] += w4.x * x4.x + w4.y * x4.y + w4.z * x4.z + w4.w * x4.w;
            }
        }
        #pragma unroll
        for (int p = 0; p < XP; ++p) {
            int P = p0 + p;
            int b = P >> 12; int l = P & (LL - 1);
            int lt = ((l & 63) << 6) | (l >> 6);
            int tk = (k == 0) ? l : (k == 1) ? lt : (k == 2) ? (LL - 1 - l) : (LL - 1 - lt);
            size_t it = ((size_t)(b * KK + k) * LL + tk);
            if (c2 < RR)            dts_raw[it * RR + c2] = acc[p];
            else if (c2 < RR + NS)  Bs[it * NS + (c2 - RR)] = acc[p];
            else                    Cs[it * NS + (c2 - RR - NS)] = acc[p];
        }
    }
}

// ---------------- K5a: chunked scan pass 1 (chunk summaries, h_in = 0) ----------------
__global__ __launch_bounds__(192) void k_scan1(const float* __restrict__ xc,
        const float* __restrict__ dts_raw, const float* __restrict__ Bsg,
        const float* __restrict__ A_logs, const float* __restrict__ dtw,
        const float* __restrict__ dtb,
        float* __restrict__ asum_g, float* __restrict__ hpart) {
    __shared__ __align__(16) float dts_s[LC * 8];
    __shared__ __align__(16) float bs_s[LC * NS];
    int bi = blockIdx.x;
    int b = bi >> 8; int rem = bi & 255; int k = rem >> 6; int c0 = rem & 63;
    int t0 = c0 * LC;
    int d = threadIdx.x;
    size_t g0 = (size_t)(b * KK + k) * LL + t0;
    for (int e = d; e < LC * RR; e += DI) dts_s[(e / RR) * 8 + (e % RR)] = dts_raw[g0 * RR + e];
    for (int e = d; e < LC * NS; e += DI) bs_s[e] = Bsg[g0 * NS + e];
    __syncthreads();
    int kd = k * DI + d;
    float Ar2[NS];
    #pragma unroll
    for (int n = 0; n < NS; ++n) Ar2[n] = -__expf(A_logs[(size_t)kd * NS + n]) * 1.44269504f;
    float dw[RR];
    #pragma unroll
    for (int r = 0; r < RR; ++r) dw[r] = dtw[kd * RR + r];
    float bias = dtb[kd];
    float h[NS];
    #pragma unroll
    for (int n = 0; n < NS; ++n) h[n] = 0.f;
    float asum = 0.f;
    const float* xcb = xc + (size_t)b * LL * DI + d;
    for (int tg = 0; tg < LC; tg += 4) {
        float uu[4];
        #pragma unroll
        for (int j = 0; j < 4; ++j) uu[j] = xcb[(size_t)lmap(k, t0 + tg + j) * DI];
        #pragma unroll
        for (int j = 0; j < 4; ++j) {
            int t = tg + j;
            float4 q4 = *(const float4*)&dts_s[t * 8];
            float2 q2 = *(const float2*)&dts_s[t * 8 + 4];
            float dtr = bias + q4.x * dw[0] + q4.y * dw[1] + q4.z * dw[2]
                             + q4.w * dw[3] + q2.x * dw[4] + q2.y * dw[5];
            float dt = fsoftplus(dtr);
            asum += dt;
            float dtu = dt * uu[j];
            #pragma unroll
            for (int n4 = 0; n4 < 4; ++n4) {
                float4 b4 = *(const float4*)&bs_s[t * NS + n4 * 4];
                h[n4*4+0] = h[n4*4+0] * rexp2(dt * Ar2[n4*4+0]) + dtu * b4.x;
                h[n4*4+1] = h[n4*4+1] * rexp2(dt * Ar2[n4*4+1]) + dtu * b4.y;
                h[n4*4+2] = h[n4*4+2] * rexp2(dt * Ar2[n4*4+2]) + dtu * b4.z;
                h[n4*4+3] = h[n4*4+3] * rexp2(dt * Ar2[n4*4+3]) + dtu * b4.w;
            }
        }
    }
    asum_g[(size_t)bi * DI + d] = asum;
    size_t base = ((size_t)bi * DI + d) * NS;
    #pragma unroll
    for (int n4 = 0; n4 < 4; ++n4) {
        float4 hv = make_float4(h[n4*4], h[n4*4+1], h[n4*4+2], h[n4*4+3]);
        *(float4*)&hpart[base + n4 * 4] = hv;
    }
}

// ---------------- K5b: propagate chunk-boundary states (in-place hpart -> hin) ----------------
__global__ __launch_bounds__(256) void k_mid(const float* __restrict__ asum_g,
        const float* __restrict__ A_logs, float* __restrict__ hpp) {
    int g = blockIdx.x * 256 + threadIdx.x;   // B*K*DI*NS threads
    int bk = g / (DI * NS);
    int rem = g % (DI * NS);
    int d = rem >> 4; int n = rem & 15;
    int k = bk & 3;
    float Ar2 = -__expf(A_logs[(size_t)(k * DI + d) * NS + n]) * 1.44269504f;
    float h = 0.f;
    for (int c = 0; c < NCH; ++c) {
        size_t row = (size_t)(bk * NCH + c) * DI + d;
        float a = rexp2(Ar2 * asum_g[row]);
        size_t ix = row * NS + n;
        float hp = hpp[ix];
        hpp[ix] = h;            // becomes hin for chunk c
        h = a * h + hp;
    }
}

// ---------------- K5c: chunked scan pass 2 (full scan, emit y, atomic merge) ----------------
__global__ __launch_bounds__(192) void k_scan2(const float* __restrict__ xc,
        const float* __restrict__ dts_raw, const float* __restrict__ Bsg,
        const float* __restrict__ Csg, const float* __restrict__ A_logs,
        const float* __restrict__ dtw, const float* __restrict__ dtb,
        const float* __restrict__ hinb, float* __restrict__ y0) {
    __shared__ __align__(16) float dts_s[LC * 8];
    __shared__ __align__(16) float bs_s[LC * NS];
    __shared__ __align__(16) float cs_s[LC * NS];
    int bi = blockIdx.x;
    int b = bi >> 8; int rem = bi & 255; int k = rem >> 6; int c0 = rem & 63;
    int t0 = c0 * LC;
    int d = threadIdx.x;
    size_t g0 = (size_t)(b * KK + k) * LL + t0;
    for (int e = d; e < LC * RR; e += DI) dts_s[(e / RR) * 8 + (e % RR)] = dts_raw[g0 * RR + e];
    for (int e = d; e < LC * NS; e += DI) bs_s[e] = Bsg[g0 * NS + e];
    for (int e = d; e < LC * NS; e += DI) cs_s[e] = Csg[g0 * NS + e];
    __syncthreads();
    int kd = k * DI + d;
    float Ar2[NS];
    #pragma unroll
    for (int n = 0; n < NS; ++n) Ar2[n] = -__expf(A_logs[(size_t)kd * NS + n]) * 1.44269504f;
    float dw[RR];
    #pragma unroll
    for (int r = 0; r < RR; ++r) dw[r] = dtw[kd * RR + r];
    float bias = dtb[kd];
    size_t base = ((size_t)bi * DI + d) * NS;
    float h[NS];
    #pragma unroll
    for (int n4 = 0; n4 < 4; ++n4) {
        float4 hv = *(const float4*)&hinb[base + n4 * 4];
        h[n4*4+0] = hv.x; h[n4*4+1] = hv.y; h[n4*4+2] = hv.z; h[n4*4+3] = hv.w;
    }
    const float* xcb = xc + (size_t)b * LL * DI + d;
    float* y0b = y0 + (size_t)b * LL * DI + d;
    for (int tg = 0; tg < LC; tg += 4) {
        float uu[4];
        int lx[4];
        #pragma unroll
        for (int j = 0; j < 4; ++j) {
            lx[j] = lmap(k, t0 + tg + j);
            uu[j] = xcb[(size_t)lx[j] * DI];
        }
        #pragma unroll
        for (int j = 0; j < 4; ++j) {
            int t = tg + j;
            float4 q4 = *(const float4*)&dts_s[t * 8];
            float2 q2 = *(const float2*)&dts_s[t * 8 + 4];
            float dtr = bias + q4.x * dw[0] + q4.y * dw[1] + q4.z * dw[2]
                             + q4.w * dw[3] + q2.x * dw[4] + q2.y * dw[5];
            float dt = fsoftplus(dtr);
            float dtu = dt * uu[j];
            float y = 0.f;
            #pragma unroll
            for (int n4 = 0; n4 < 4; ++n4) {
                float4 b4 = *(const float4*)&bs_s[t * NS + n4 * 4];
                float4 c4 = *(const float4*)&cs_s[t * NS + n4 * 4];
                h[n4*4+0] = h[n4*4+0] * rexp2(dt * Ar2[n4*4+0]) + dtu * b4.x;
                h[n4*4+1] = h[n4*4+1] * rexp2(dt * Ar2[n4*4+1]) + dtu * b4.y;
                h[n4*4+2] = h[n4*4+2] * rexp2(dt * Ar2[n4*4+2]) + dtu * b4.z;
                h[n4*4+3] = h[n4*4+3] * rexp2(dt * Ar2[n4*4+3]) + dtu * b4.w;
                y += h[n4*4+0] * c4.x + h[n4*4+1] * c4.y + h[n4*4+2] * c4.z + h[n4*4+3] * c4.w;
            }
            atomicAdd(&y0b[(size_t)lx[j] * DI], y);
        }
    }
}

// ---------------- K6: LayerNorm + gate + out_proj (register-tiled GEMM) ----------------
__global__ __launch_bounds__(256) void k_final(const float* __restrict__ y0,
        const float* __restrict__ zs, const float* __restrict__ nw,
        const float* __restrict__ nb, const float* __restrict__ Wout,
        float* __restrict__ out) {
    __shared__ __align__(16) float gs[32][DI];
    int tid = threadIdx.x;
    int wv = tid >> 6, lane = tid & 63;
    int Pbase = blockIdx.x * 32;
    float nwv[3], nbv[3];
    #pragma unroll
    for (int j = 0; j < 3; ++j) { nwv[j] = nw[lane + 64 * j]; nbv[j] = nb[lane + 64 * j]; }
    for (int pi = 0; pi < 8; ++pi) {
        int pl = wv * 8 + pi;
        size_t Poff = (size_t)(Pbase + pl) * DI;
        float v[3];
        #pragma unroll
        for (int j = 0; j < 3; ++j) v[j] = y0[Poff + lane + 64 * j];
        float s = v[0] + v[1] + v[2];
        #pragma unroll
        for (int o = 32; o; o >>= 1) s += __shfl_xor(s, o);
        float mean = s * (1.f / 192.f);
        float ss = 0.f;
        #pragma unroll
        for (int j = 0; j < 3; ++j) { float dd = v[j] - mean; ss += dd * dd; }
        #pragma unroll
        for (int o = 32; o; o >>= 1) ss += __shfl_xor(ss, o);
        float rstd = rsqrtf(ss * (1.f / 192.f) + EPSN);
        #pragma unroll
        for (int j = 0; j < 3; ++j) {
            int c = lane + 64 * j;
            gs[pl][c] = ((v[j] - mean) * rstd * nwv[j] + nbv[j]) * zs[Poff + c];
        }
    }
    __syncthreads();
    int o = tid & 127;
    int pg = tid >> 7;
    if (o < DM) {
        const float* wr = Wout + (size_t)o * DI;
        float acc[16];
        #pragma unroll
        for (int p = 0; p < 16; ++p) acc[p] = 0.f;
        for (int k0 = 0; k0 < DI; k0 += 4) {
            float4 w4 = *(const float4*)(wr + k0);
            #pragma unroll
            for (int p = 0; p < 16; ++p) {
                float4 g4 = *(const float4*)(&gs[pg * 16 + p][k0]);
                acc[p] += w4.x * g4.x + w4.y * g4.y + w4.z * g4.z + w4.w * g4.w;
            }
        }
        #pragma unroll
        for (int p = 0; p < 16; ++p)
            out[(size_t)(Pbase + pg * 16 + p) * DM + o] = acc[p];
    }
}

extern "C" void kernel_launch(void* const* d_in, const int* in_sizes, int n_in,
                              void* d_out, int out_size, void* d_ws, size_t ws_size,
                              hipStream_t stream) {
    const float* x      = (const float*)d_in[0];
    const float* in_w   = (const float*)d_in[1];
    const float* conv_w = (const float*)d_in[2];
    const float* conv_b = (const float*)d_in[3];
    const float* xpw    = (const float*)d_in[4];
    const float* dtw    = (const float*)d_in[5];
    const float* A_logs = (const float*)d_in[6];
    const float* Ds     = (const float*)d_in[7];
    const float* dtb    = (const float*)d_in[8];
    const float* nw     = (const float*)d_in[9];
    const float* nb     = (const float*)d_in[10];
    const float* out_w  = (const float*)d_in[11];
    float* out = (float*)d_out;

    char* ws = (char*)d_ws;
    size_t off = 0;
    auto alloc = [&](size_t n) { float* p = (float*)(ws + off); off += n * sizeof(float); return p; };
    float* xx   = alloc((size_t)BB * LL * DI);
    float* zs   = alloc((size_t)BB * LL * DI);
    float* xc   = alloc((size_t)BB * LL * DI);
    float* y0   = alloc((size_t)BB * LL * DI);
    float* dts  = alloc((size_t)BB * KK * LL * RR);
    float* Bsb  = alloc((size_t)BB * KK * LL * NS);
    float* Csb  = alloc((size_t)BB * KK * LL * NS);
    float* asum = alloc((size_t)BB * KK * NCH * DI);
    float* hpp  = alloc((size_t)BB * KK * NCH * DI * NS);

    k_inproj<<<BB * LL / 8, 384, 0, stream>>>(x, in_w, xx, zs);
    k_conv<<<BB * LL * DI / 256, 256, 0, stream>>>(xx, conv_w, conv_b, Ds, xc, y0);
    k_xdbl<<<BB * LL / XP, 192, 0, stream>>>(xc, xpw, dts, Bsb, Csb);
    k_scan1<<<BB * KK * NCH, DI, 0, stream>>>(xc, dts, Bsb, A_logs, dtw, dtb, asum, hpp);
    k_mid<<<(BB * KK * DI * NS) / 256, 256, 0, stream>>>(asum, A_logs, hpp);
    k_scan2<<<BB * KK * NCH, DI, 0, stream>>>(xc, dts, Bsb, Csb, A_logs, dtw, dtb, hpp, y0);
    k_final<<<BB * LL / 32, 256, 0, stream>>>(y0, zs, nw, nb, out_w, out);
}